// Round 12
// baseline (323.600 us; speedup 1.0000x reference)
//
#include <hip/hip_runtime.h>
#include <hip/hip_bf16.h>

#define N_NODES 20000
#define N_EDGES 320000
#define NEG_SLOPE 0.2f

__device__ __forceinline__ unsigned int bf16pack(float a, float b) {
    unsigned int ua = __float_as_uint(a);
    ua = (ua + 0x7fffu + ((ua >> 16) & 1u)) >> 16;
    unsigned int ub = __float_as_uint(b);
    ub = (ub + 0x7fffu + ((ub >> 16) & 1u)) >> 16;
    return ua | (ub << 16);
}

// ---------------- CSR build (by dst) ----------------
__global__ void hist_kernel(const int* __restrict__ dst, int* __restrict__ deg) {
    int e = blockIdx.x * blockDim.x + threadIdx.x;
    if (e < N_EDGES) atomicAdd(&deg[dst[e]], 1);
}

__global__ __launch_bounds__(1024) void scan_kernel(const int* __restrict__ deg,
                                                    int* __restrict__ offsets,
                                                    int* __restrict__ pos) {
    __shared__ int sums[1024];
    const int CH = (N_NODES + 1023) / 1024;  // 20
    int t = threadIdx.x;
    int beg = t * CH;
    int end = min(beg + CH, N_NODES);
    int loc[20];
    int s = 0;
    for (int i = beg; i < end; ++i) { loc[i - beg] = s; s += deg[i]; }
    sums[t] = s;
    __syncthreads();
    for (int st = 1; st < 1024; st <<= 1) {
        int v = (t >= st) ? sums[t - st] : 0;
        __syncthreads();
        sums[t] += v;
        __syncthreads();
    }
    int excl = (t == 0) ? 0 : sums[t - 1];
    for (int i = beg; i < end; ++i) {
        int o = excl + loc[i - beg];
        offsets[i] = o;
        pos[i] = o;
    }
    if (t == 1023) offsets[N_NODES] = sums[1023];
}

__global__ void scatter_kernel(const int* __restrict__ src, const int* __restrict__ dst,
                               int* __restrict__ pos, int* __restrict__ elist) {
    int e = blockIdx.x * blockDim.x + threadIdx.x;
    if (e < N_EDGES) {
        int p = atomicAdd(&pos[dst[e]], 1);
        elist[p] = src[e];
    }
}

// ------------- GEMM1: h1 = X[N,128] @ W1[128,384] (bf16-packed); el1/er1[N,3] -------------
// 16 rows x 128 cols (one head) per block, 256 threads, 2x4 micro-tile.
// grid = (20000/16, 3). LDS row-major [16][132]: b128 writes/reads, conflict-free.
__global__ __launch_bounds__(256) void gemm1_kernel(const float* __restrict__ X,
                                                    const float* __restrict__ W,
                                                    const float* __restrict__ al,
                                                    const float* __restrict__ ar,
                                                    uint2* __restrict__ H1b,
                                                    float* __restrict__ EL,
                                                    float* __restrict__ ER) {
    __shared__ float xs[16][132];
    int tid = threadIdx.x;
    int tm = tid >> 5;        // 0..7 -> rows tm*2, tm*2+1
    int tn = tid & 31;        // cols tn*4..tn*4+3
    int row0 = blockIdx.x * 16;
    int head = blockIdx.y;
    int n0 = head * 128;

#pragma unroll
    for (int j = 0; j < 2; ++j) {
        int idx = tid + j * 256;
        int m = idx >> 5, k4 = idx & 31;
        *(float4*)&xs[m][k4 * 4] = *(const float4*)&X[(size_t)(row0 + m) * 128 + k4 * 4];
    }
    __syncthreads();

    int ra = tm * 2, rb = ra + 1;
    float acc[2][4] = {};
    const float* Wp = W + n0 + tn * 4;
    for (int k4 = 0; k4 < 32; ++k4) {
        float4 xa = *(const float4*)&xs[ra][k4 * 4];
        float4 xb = *(const float4*)&xs[rb][k4 * 4];
        float xav[4] = {xa.x, xa.y, xa.z, xa.w};
        float xbv[4] = {xb.x, xb.y, xb.z, xb.w};
#pragma unroll
        for (int kk = 0; kk < 4; ++kk) {
            float4 w = *(const float4*)&Wp[(size_t)(k4 * 4 + kk) * 384];
            float wv[4] = {w.x, w.y, w.z, w.w};
#pragma unroll
            for (int c = 0; c < 4; ++c) {
                acc[0][c] = fmaf(xav[kk], wv[c], acc[0][c]);
                acc[1][c] = fmaf(xbv[kk], wv[c], acc[1][c]);
            }
        }
    }

    float4 av = *(const float4*)&al[n0 + tn * 4];
    float4 rv = *(const float4*)&ar[n0 + tn * 4];
    float avv[4] = {av.x, av.y, av.z, av.w};
    float rvv[4] = {rv.x, rv.y, rv.z, rv.w};
#pragma unroll
    for (int r = 0; r < 2; ++r) {
        int row = row0 + ra + r;
        uint2 pk;
        pk.x = bf16pack(acc[r][0], acc[r][1]);
        pk.y = bf16pack(acc[r][2], acc[r][3]);
        H1b[(size_t)row * 96 + head * 32 + tn] = pk;
        float vl = acc[r][0] * avv[0] + acc[r][1] * avv[1] + acc[r][2] * avv[2] + acc[r][3] * avv[3];
        float vr = acc[r][0] * rvv[0] + acc[r][1] * rvv[1] + acc[r][2] * rvv[2] + acc[r][3] * rvv[3];
#pragma unroll
        for (int s = 16; s > 0; s >>= 1) {
            vl += __shfl_down(vl, s, 32);
            vr += __shfl_down(vr, s, 32);
        }
        if (tn == 0) {
            EL[row * 3 + head] = vl;
            ER[row * 3 + head] = vr;
        }
    }
}

// ------------- GEMM2: h2 = X2[N,384] @ W2[384,128] (bf16-packed); el2/er2[N] -------------
// 16 rows x 128 cols per block, K in 3 chunks of 128. grid = 20000/16 = 1250.
__global__ __launch_bounds__(256) void gemm2_kernel(const float* __restrict__ X2,
                                                    const float* __restrict__ W,
                                                    const float* __restrict__ al,
                                                    const float* __restrict__ ar,
                                                    uint2* __restrict__ H2b,
                                                    float* __restrict__ EL,
                                                    float* __restrict__ ER) {
    __shared__ float xs[16][132];
    int tid = threadIdx.x;
    int tm = tid >> 5;
    int tn = tid & 31;
    int row0 = blockIdx.x * 16;
    int ra = tm * 2, rb = ra + 1;

    float acc[2][4] = {};
    for (int c = 0; c < 3; ++c) {
#pragma unroll
        for (int j = 0; j < 2; ++j) {
            int idx = tid + j * 256;
            int m = idx >> 5, k4 = idx & 31;
            *(float4*)&xs[m][k4 * 4] =
                *(const float4*)&X2[(size_t)(row0 + m) * 384 + c * 128 + k4 * 4];
        }
        __syncthreads();
        const float* Wp = W + (size_t)c * 128 * 128 + tn * 4;
        for (int k4 = 0; k4 < 32; ++k4) {
            float4 xa = *(const float4*)&xs[ra][k4 * 4];
            float4 xb = *(const float4*)&xs[rb][k4 * 4];
            float xav[4] = {xa.x, xa.y, xa.z, xa.w};
            float xbv[4] = {xb.x, xb.y, xb.z, xb.w};
#pragma unroll
            for (int kk = 0; kk < 4; ++kk) {
                float4 w = *(const float4*)&Wp[(size_t)(k4 * 4 + kk) * 128];
                float wv[4] = {w.x, w.y, w.z, w.w};
#pragma unroll
                for (int cc = 0; cc < 4; ++cc) {
                    acc[0][cc] = fmaf(xav[kk], wv[cc], acc[0][cc]);
                    acc[1][cc] = fmaf(xbv[kk], wv[cc], acc[1][cc]);
                }
            }
        }
        __syncthreads();
    }

    float4 av = *(const float4*)&al[tn * 4];
    float4 rv = *(const float4*)&ar[tn * 4];
    float avv[4] = {av.x, av.y, av.z, av.w};
    float rvv[4] = {rv.x, rv.y, rv.z, rv.w};
#pragma unroll
    for (int r = 0; r < 2; ++r) {
        int row = row0 + ra + r;
        uint2 pk;
        pk.x = bf16pack(acc[r][0], acc[r][1]);
        pk.y = bf16pack(acc[r][2], acc[r][3]);
        H2b[(size_t)row * 32 + tn] = pk;
        float vl = acc[r][0] * avv[0] + acc[r][1] * avv[1] + acc[r][2] * avv[2] + acc[r][3] * avv[3];
        float vr = acc[r][0] * rvv[0] + acc[r][1] * rvv[1] + acc[r][2] * rvv[2] + acc[r][3] * rvv[3];
#pragma unroll
        for (int s = 16; s > 0; s >>= 1) {
            vl += __shfl_down(vl, s, 32);
            vr += __shfl_down(vr, s, 32);
        }
        if (tn == 0) {
            EL[row] = vl;
            ER[row] = vr;
        }
    }
}

// ------------- Layer-1 fused edge-softmax + aggregate (bf16 gathers) -------------
// 192 threads: wave hd owns head hd; lane q owns feature pair (2q,2q+1).
__global__ __launch_bounds__(192) void agg1_kernel(const unsigned int* __restrict__ H1b,
                                                   const float* __restrict__ EL,
                                                   const float* __restrict__ ER,
                                                   const int* __restrict__ offsets,
                                                   const int* __restrict__ elist,
                                                   const float* __restrict__ bias,
                                                   float2* __restrict__ OUT2) {
    __shared__ int s_src[128];
    __shared__ float s_sc[3][128];
    __shared__ float s_w[3][128];
    int n = blockIdx.x;
    int t = threadIdx.x;
    int hd = t >> 6;
    int q  = t & 63;
    int o0 = offsets[n], o1 = offsets[n + 1];
    int deg = o1 - o0;
    float er0 = ER[n * 3 + 0], er1v = ER[n * 3 + 1], er2v = ER[n * 3 + 2];
    float m = -1e30f, l = 0.f, alo = 0.f, ahi = 0.f;
    for (int base = 0; base < deg; base += 128) {
        int cnt = min(128, deg - base);
        if (t < cnt) {
            int s = elist[o0 + base + t];
            s_src[t] = s;
            float e0 = EL[s * 3 + 0] + er0;
            float e1 = EL[s * 3 + 1] + er1v;
            float e2 = EL[s * 3 + 2] + er2v;
            s_sc[0][t] = e0 > 0.f ? e0 : NEG_SLOPE * e0;
            s_sc[1][t] = e1 > 0.f ? e1 : NEG_SLOPE * e1;
            s_sc[2][t] = e2 > 0.f ? e2 : NEG_SLOPE * e2;
        }
        __syncthreads();
        float nm = m;
        for (int i = 0; i < cnt; ++i) nm = fmaxf(nm, s_sc[hd][i]);
        float f = __expf(m - nm);
        alo *= f; ahi *= f; l *= f;
        m = nm;
        if (q < cnt)      s_w[hd][q]      = __expf(s_sc[hd][q] - m);
        if (q + 64 < cnt) s_w[hd][q + 64] = __expf(s_sc[hd][q + 64] - m);
        __syncthreads();
        for (int i = 0; i < cnt; ++i) {
            float w = s_w[hd][i];
            l += w;
            unsigned int v = H1b[(size_t)s_src[i] * 192 + hd * 64 + q];
            float lo = __uint_as_float(v << 16);
            float hi = __uint_as_float(v & 0xffff0000u);
            alo = fmaf(w, lo, alo);
            ahi = fmaf(w, hi, ahi);
        }
        __syncthreads();
    }
    int b0 = hd * 128 + 2 * q;
    OUT2[(size_t)n * 192 + hd * 64 + q] = make_float2(alo / l + bias[b0], ahi / l + bias[b0 + 1]);
}

// ------------- Layer-2 fused edge-softmax + aggregate (bf16 gathers, 1 wave) -------------
__global__ __launch_bounds__(64) void agg2_kernel(const unsigned int* __restrict__ H2b,
                                                  const float* __restrict__ EL,
                                                  const float* __restrict__ ER,
                                                  const int* __restrict__ offsets,
                                                  const int* __restrict__ elist,
                                                  const float* __restrict__ bias,
                                                  float2* __restrict__ OUT2) {
    __shared__ int s_src[128];
    __shared__ float s_sc[128];
    __shared__ float s_w[128];
    int n = blockIdx.x;
    int t = threadIdx.x;  // feature pair (2t, 2t+1)
    int o0 = offsets[n], o1 = offsets[n + 1];
    int deg = o1 - o0;
    float ern = ER[n];
    float m = -1e30f, l = 0.f, alo = 0.f, ahi = 0.f;
    for (int base = 0; base < deg; base += 128) {
        int cnt = min(128, deg - base);
        for (int u = t; u < cnt; u += 64) {
            int s = elist[o0 + base + u];
            s_src[u] = s;
            float e = EL[s] + ern;
            s_sc[u] = e > 0.f ? e : NEG_SLOPE * e;
        }
        __syncthreads();
        float nm = m;
        for (int i = 0; i < cnt; ++i) nm = fmaxf(nm, s_sc[i]);
        float f = __expf(m - nm);
        alo *= f; ahi *= f; l *= f;
        m = nm;
        for (int u = t; u < cnt; u += 64) s_w[u] = __expf(s_sc[u] - m);
        __syncthreads();
        for (int i = 0; i < cnt; ++i) {
            float w = s_w[i];
            l += w;
            unsigned int v = H2b[(size_t)s_src[i] * 64 + t];
            float lo = __uint_as_float(v << 16);
            float hi = __uint_as_float(v & 0xffff0000u);
            alo = fmaf(w, lo, alo);
            ahi = fmaf(w, hi, ahi);
        }
        __syncthreads();
    }
    OUT2[(size_t)n * 64 + t] = make_float2(alo / l + bias[2 * t], ahi / l + bias[2 * t + 1]);
}

extern "C" void kernel_launch(void* const* d_in, const int* in_sizes, int n_in,
                              void* d_out, int out_size, void* d_ws, size_t ws_size,
                              hipStream_t stream) {
    const float* feats = (const float*)d_in[0];
    const float* W1    = (const float*)d_in[1];
    const float* al1   = (const float*)d_in[2];
    const float* ar1   = (const float*)d_in[3];
    const float* b1    = (const float*)d_in[4];
    const float* W2    = (const float*)d_in[5];
    const float* al2   = (const float*)d_in[6];
    const float* ar2   = (const float*)d_in[7];
    const float* b2    = (const float*)d_in[8];
    const int* src     = (const int*)d_in[9];
    const int* dst     = (const int*)d_in[10];
    float* out = (float*)d_out;

    char* ws = (char*)d_ws;
    size_t off = 0;
    auto alloc = [&](size_t bytes) {
        void* p = ws + off;
        off += (bytes + 255) & ~(size_t)255;
        return p;
    };
    unsigned int* h1b = (unsigned int*)alloc((size_t)N_NODES * 192 * 4);  // bf16 h1; reused as h2b
    float* x2  = (float*)alloc((size_t)N_NODES * 384 * 4);
    float* el1 = (float*)alloc((size_t)N_NODES * 3 * 4);
    float* er1 = (float*)alloc((size_t)N_NODES * 3 * 4);
    float* el2 = (float*)alloc((size_t)N_NODES * 4);
    float* er2 = (float*)alloc((size_t)N_NODES * 4);
    int* deg     = (int*)alloc((size_t)N_NODES * 4);
    int* offsets = (int*)alloc((size_t)(N_NODES + 1) * 4);
    int* pos     = (int*)alloc((size_t)N_NODES * 4);
    int* elist   = (int*)alloc((size_t)N_EDGES * 4);
    unsigned int* h2b = h1b;  // h1b dead after agg1; 15.4MB >= 5.1MB needed

    hipMemsetAsync(deg, 0, (size_t)N_NODES * 4, stream);
    hist_kernel<<<(N_EDGES + 255) / 256, 256, 0, stream>>>(dst, deg);
    scan_kernel<<<1, 1024, 0, stream>>>(deg, offsets, pos);
    scatter_kernel<<<(N_EDGES + 255) / 256, 256, 0, stream>>>(src, dst, pos, elist);

    dim3 g1(N_NODES / 16, 3);
    gemm1_kernel<<<g1, 256, 0, stream>>>(feats, W1, al1, ar1, (uint2*)h1b, el1, er1);
    agg1_kernel<<<N_NODES, 192, 0, stream>>>(h1b, el1, er1, offsets, elist, b1, (float2*)x2);
    gemm2_kernel<<<N_NODES / 16, 256, 0, stream>>>(x2, W2, al2, ar2, (uint2*)h2b, el2, er2);
    agg2_kernel<<<N_NODES, 64, 0, stream>>>(h2b, el2, er2, offsets, elist, b2, (float2*)out);
}

// Round 14
// 278.712 us; speedup vs baseline: 1.1611x; 1.1611x over previous
//
#include <hip/hip_runtime.h>
#include <hip/hip_bf16.h>

#define N_NODES 20000
#define N_EDGES 320000
#define NEG_SLOPE 0.2f

__device__ __forceinline__ unsigned int bf16pack(float a, float b) {
    unsigned int ua = __float_as_uint(a);
    ua = (ua + 0x7fffu + ((ua >> 16) & 1u)) >> 16;
    unsigned int ub = __float_as_uint(b);
    ub = (ub + 0x7fffu + ((ub >> 16) & 1u)) >> 16;
    return ua | (ub << 16);
}

// ---------------- CSR build (by dst) ----------------
__global__ void hist_kernel(const int* __restrict__ dst, int* __restrict__ deg) {
    int e = blockIdx.x * blockDim.x + threadIdx.x;
    if (e < N_EDGES) atomicAdd(&deg[dst[e]], 1);
}

__global__ __launch_bounds__(1024) void scan_kernel(const int* __restrict__ deg,
                                                    int* __restrict__ offsets,
                                                    int* __restrict__ pos) {
    __shared__ int sums[1024];
    const int CH = (N_NODES + 1023) / 1024;  // 20
    int t = threadIdx.x;
    int beg = t * CH;
    int end = min(beg + CH, N_NODES);
    int loc[20];
    int s = 0;
    for (int i = beg; i < end; ++i) { loc[i - beg] = s; s += deg[i]; }
    sums[t] = s;
    __syncthreads();
    for (int st = 1; st < 1024; st <<= 1) {
        int v = (t >= st) ? sums[t - st] : 0;
        __syncthreads();
        sums[t] += v;
        __syncthreads();
    }
    int excl = (t == 0) ? 0 : sums[t - 1];
    for (int i = beg; i < end; ++i) {
        int o = excl + loc[i - beg];
        offsets[i] = o;
        pos[i] = o;
    }
    if (t == 1023) offsets[N_NODES] = sums[1023];
}

__global__ void scatter_kernel(const int* __restrict__ src, const int* __restrict__ dst,
                               int* __restrict__ pos, int* __restrict__ elist) {
    int e = blockIdx.x * blockDim.x + threadIdx.x;
    if (e < N_EDGES) {
        int p = atomicAdd(&pos[dst[e]], 1);
        elist[p] = src[e];
    }
}

// ------------- GEMM1: h1 = X[N,128] @ W1[128,384] (bf16-packed); el1/er1[N,3] -------------
// 40 rows x 128 cols (one head) per block, 256 threads, 5x4 micro-tile.
// grid = (500, 3). LDS row-major [40][132]: b128 writes/reads, conflict-free.
__global__ __launch_bounds__(256) void gemm1_kernel(const float* __restrict__ X,
                                                    const float* __restrict__ W,
                                                    const float* __restrict__ al,
                                                    const float* __restrict__ ar,
                                                    uint2* __restrict__ H1b,
                                                    float* __restrict__ EL,
                                                    float* __restrict__ ER) {
    __shared__ float xs[40][132];
    int tid = threadIdx.x;
    int tm = tid >> 5;        // 0..7 -> rows tm*5..tm*5+4
    int tn = tid & 31;        // cols tn*4..tn*4+3
    int row0 = blockIdx.x * 40;
    int head = blockIdx.y;
    int n0 = head * 128;

#pragma unroll
    for (int j = 0; j < 5; ++j) {
        int idx = tid + j * 256;
        int m = idx >> 5, k4 = idx & 31;
        *(float4*)&xs[m][k4 * 4] = *(const float4*)&X[(size_t)(row0 + m) * 128 + k4 * 4];
    }
    __syncthreads();

    int ra = tm * 5;
    float acc[5][4] = {};
    const float* Wp = W + n0 + tn * 4;
    for (int k4 = 0; k4 < 32; ++k4) {
        float xv[5][4];
#pragma unroll
        for (int r = 0; r < 5; ++r) {
            float4 x = *(const float4*)&xs[ra + r][k4 * 4];
            xv[r][0] = x.x; xv[r][1] = x.y; xv[r][2] = x.z; xv[r][3] = x.w;
        }
#pragma unroll
        for (int kk = 0; kk < 4; ++kk) {
            float4 w = *(const float4*)&Wp[(size_t)(k4 * 4 + kk) * 384];
            float wv[4] = {w.x, w.y, w.z, w.w};
#pragma unroll
            for (int r = 0; r < 5; ++r)
#pragma unroll
                for (int c = 0; c < 4; ++c)
                    acc[r][c] = fmaf(xv[r][kk], wv[c], acc[r][c]);
        }
    }

    float4 av = *(const float4*)&al[n0 + tn * 4];
    float4 rv = *(const float4*)&ar[n0 + tn * 4];
    float avv[4] = {av.x, av.y, av.z, av.w};
    float rvv[4] = {rv.x, rv.y, rv.z, rv.w};
#pragma unroll
    for (int r = 0; r < 5; ++r) {
        int row = row0 + ra + r;
        uint2 pk;
        pk.x = bf16pack(acc[r][0], acc[r][1]);
        pk.y = bf16pack(acc[r][2], acc[r][3]);
        H1b[(size_t)row * 96 + head * 32 + tn] = pk;
        float vl = acc[r][0] * avv[0] + acc[r][1] * avv[1] + acc[r][2] * avv[2] + acc[r][3] * avv[3];
        float vr = acc[r][0] * rvv[0] + acc[r][1] * rvv[1] + acc[r][2] * rvv[2] + acc[r][3] * rvv[3];
#pragma unroll
        for (int s = 16; s > 0; s >>= 1) {
            vl += __shfl_down(vl, s, 32);
            vr += __shfl_down(vr, s, 32);
        }
        if (tn == 0) {
            EL[row * 3 + head] = vl;
            ER[row * 3 + head] = vr;
        }
    }
}

// ------------- GEMM2: h2 = X2[N,384] @ W2[384,128] (bf16-packed); el2/er2[N] -------------
// 40 rows x 128 cols per block, K in 3 chunks of 128. grid = 500.
__global__ __launch_bounds__(256) void gemm2_kernel(const float* __restrict__ X2,
                                                    const float* __restrict__ W,
                                                    const float* __restrict__ al,
                                                    const float* __restrict__ ar,
                                                    uint2* __restrict__ H2b,
                                                    float* __restrict__ EL,
                                                    float* __restrict__ ER) {
    __shared__ float xs[40][132];
    int tid = threadIdx.x;
    int tm = tid >> 5;
    int tn = tid & 31;
    int row0 = blockIdx.x * 40;
    int ra = tm * 5;

    float acc[5][4] = {};
    const float* Wp = W + tn * 4;
    for (int c = 0; c < 3; ++c) {
#pragma unroll
        for (int j = 0; j < 5; ++j) {
            int idx = tid + j * 256;
            int m = idx >> 5, k4 = idx & 31;
            *(float4*)&xs[m][k4 * 4] =
                *(const float4*)&X2[(size_t)(row0 + m) * 384 + c * 128 + k4 * 4];
        }
        __syncthreads();
        for (int k4 = 0; k4 < 32; ++k4) {
            float xv[5][4];
#pragma unroll
            for (int r = 0; r < 5; ++r) {
                float4 x = *(const float4*)&xs[ra + r][k4 * 4];
                xv[r][0] = x.x; xv[r][1] = x.y; xv[r][2] = x.z; xv[r][3] = x.w;
            }
#pragma unroll
            for (int kk = 0; kk < 4; ++kk) {
                float4 w = *(const float4*)&Wp[(size_t)(c * 128 + k4 * 4 + kk) * 128];
                float wv[4] = {w.x, w.y, w.z, w.w};
#pragma unroll
                for (int r = 0; r < 5; ++r)
#pragma unroll
                    for (int cc = 0; cc < 4; ++cc)
                        acc[r][cc] = fmaf(xv[r][kk], wv[cc], acc[r][cc]);
            }
        }
        __syncthreads();
    }

    float4 av = *(const float4*)&al[tn * 4];
    float4 rv = *(const float4*)&ar[tn * 4];
    float avv[4] = {av.x, av.y, av.z, av.w};
    float rvv[4] = {rv.x, rv.y, rv.z, rv.w};
#pragma unroll
    for (int r = 0; r < 5; ++r) {
        int row = row0 + ra + r;
        uint2 pk;
        pk.x = bf16pack(acc[r][0], acc[r][1]);
        pk.y = bf16pack(acc[r][2], acc[r][3]);
        H2b[(size_t)row * 32 + tn] = pk;
        float vl = acc[r][0] * avv[0] + acc[r][1] * avv[1] + acc[r][2] * avv[2] + acc[r][3] * avv[3];
        float vr = acc[r][0] * rvv[0] + acc[r][1] * rvv[1] + acc[r][2] * rvv[2] + acc[r][3] * rvv[3];
#pragma unroll
        for (int s = 16; s > 0; s >>= 1) {
            vl += __shfl_down(vl, s, 32);
            vr += __shfl_down(vr, s, 32);
        }
        if (tn == 0) {
            EL[row] = vl;
            ER[row] = vr;
        }
    }
}

// ------------- Layer-1 fused edge-softmax + aggregate (bf16 gathers) -------------
// 192 threads: wave hd owns head hd; lane q owns feature pair (2q,2q+1).
__global__ __launch_bounds__(192) void agg1_kernel(const unsigned int* __restrict__ H1b,
                                                   const float* __restrict__ EL,
                                                   const float* __restrict__ ER,
                                                   const int* __restrict__ offsets,
                                                   const int* __restrict__ elist,
                                                   const float* __restrict__ bias,
                                                   float2* __restrict__ OUT2) {
    __shared__ int s_src[128];
    __shared__ float s_sc[3][128];
    __shared__ float s_w[3][128];
    int n = blockIdx.x;
    int t = threadIdx.x;
    int hd = t >> 6;
    int q  = t & 63;
    int o0 = offsets[n], o1 = offsets[n + 1];
    int deg = o1 - o0;
    float er0 = ER[n * 3 + 0], er1v = ER[n * 3 + 1], er2v = ER[n * 3 + 2];
    float m = -1e30f, l = 0.f, alo = 0.f, ahi = 0.f;
    for (int base = 0; base < deg; base += 128) {
        int cnt = min(128, deg - base);
        if (t < cnt) {
            int s = elist[o0 + base + t];
            s_src[t] = s;
            float e0 = EL[s * 3 + 0] + er0;
            float e1 = EL[s * 3 + 1] + er1v;
            float e2 = EL[s * 3 + 2] + er2v;
            s_sc[0][t] = e0 > 0.f ? e0 : NEG_SLOPE * e0;
            s_sc[1][t] = e1 > 0.f ? e1 : NEG_SLOPE * e1;
            s_sc[2][t] = e2 > 0.f ? e2 : NEG_SLOPE * e2;
        }
        __syncthreads();
        float nm = m;
        for (int i = 0; i < cnt; ++i) nm = fmaxf(nm, s_sc[hd][i]);
        float f = __expf(m - nm);
        alo *= f; ahi *= f; l *= f;
        m = nm;
        if (q < cnt)      s_w[hd][q]      = __expf(s_sc[hd][q] - m);
        if (q + 64 < cnt) s_w[hd][q + 64] = __expf(s_sc[hd][q + 64] - m);
        __syncthreads();
        for (int i = 0; i < cnt; ++i) {
            float w = s_w[hd][i];
            l += w;
            unsigned int v = H1b[(size_t)s_src[i] * 192 + hd * 64 + q];
            float lo = __uint_as_float(v << 16);
            float hi = __uint_as_float(v & 0xffff0000u);
            alo = fmaf(w, lo, alo);
            ahi = fmaf(w, hi, ahi);
        }
        __syncthreads();
    }
    int b0 = hd * 128 + 2 * q;
    OUT2[(size_t)n * 192 + hd * 64 + q] = make_float2(alo / l + bias[b0], ahi / l + bias[b0 + 1]);
}

// ------------- Layer-2 fused edge-softmax + aggregate (bf16 gathers, 1 wave) -------------
__global__ __launch_bounds__(64) void agg2_kernel(const unsigned int* __restrict__ H2b,
                                                  const float* __restrict__ EL,
                                                  const float* __restrict__ ER,
                                                  const int* __restrict__ offsets,
                                                  const int* __restrict__ elist,
                                                  const float* __restrict__ bias,
                                                  float2* __restrict__ OUT2) {
    __shared__ int s_src[128];
    __shared__ float s_sc[128];
    __shared__ float s_w[128];
    int n = blockIdx.x;
    int t = threadIdx.x;  // feature pair (2t, 2t+1)
    int o0 = offsets[n], o1 = offsets[n + 1];
    int deg = o1 - o0;
    float ern = ER[n];
    float m = -1e30f, l = 0.f, alo = 0.f, ahi = 0.f;
    for (int base = 0; base < deg; base += 128) {
        int cnt = min(128, deg - base);
        for (int u = t; u < cnt; u += 64) {
            int s = elist[o0 + base + u];
            s_src[u] = s;
            float e = EL[s] + ern;
            s_sc[u] = e > 0.f ? e : NEG_SLOPE * e;
        }
        __syncthreads();
        float nm = m;
        for (int i = 0; i < cnt; ++i) nm = fmaxf(nm, s_sc[i]);
        float f = __expf(m - nm);
        alo *= f; ahi *= f; l *= f;
        m = nm;
        for (int u = t; u < cnt; u += 64) s_w[u] = __expf(s_sc[u] - m);
        __syncthreads();
        for (int i = 0; i < cnt; ++i) {
            float w = s_w[i];
            l += w;
            unsigned int v = H2b[(size_t)s_src[i] * 64 + t];
            float lo = __uint_as_float(v << 16);
            float hi = __uint_as_float(v & 0xffff0000u);
            alo = fmaf(w, lo, alo);
            ahi = fmaf(w, hi, ahi);
        }
        __syncthreads();
    }
    OUT2[(size_t)n * 64 + t] = make_float2(alo / l + bias[2 * t], ahi / l + bias[2 * t + 1]);
}

extern "C" void kernel_launch(void* const* d_in, const int* in_sizes, int n_in,
                              void* d_out, int out_size, void* d_ws, size_t ws_size,
                              hipStream_t stream) {
    const float* feats = (const float*)d_in[0];
    const float* W1    = (const float*)d_in[1];
    const float* al1   = (const float*)d_in[2];
    const float* ar1   = (const float*)d_in[3];
    const float* b1    = (const float*)d_in[4];
    const float* W2    = (const float*)d_in[5];
    const float* al2   = (const float*)d_in[6];
    const float* ar2   = (const float*)d_in[7];
    const float* b2    = (const float*)d_in[8];
    const int* src     = (const int*)d_in[9];
    const int* dst     = (const int*)d_in[10];
    float* out = (float*)d_out;

    char* ws = (char*)d_ws;
    size_t off = 0;
    auto alloc = [&](size_t bytes) {
        void* p = ws + off;
        off += (bytes + 255) & ~(size_t)255;
        return p;
    };
    unsigned int* h1b = (unsigned int*)alloc((size_t)N_NODES * 192 * 4);  // bf16 h1; reused as h2b
    float* x2  = (float*)alloc((size_t)N_NODES * 384 * 4);
    float* el1 = (float*)alloc((size_t)N_NODES * 3 * 4);
    float* er1 = (float*)alloc((size_t)N_NODES * 3 * 4);
    float* el2 = (float*)alloc((size_t)N_NODES * 4);
    float* er2 = (float*)alloc((size_t)N_NODES * 4);
    int* deg     = (int*)alloc((size_t)N_NODES * 4);
    int* offsets = (int*)alloc((size_t)(N_NODES + 1) * 4);
    int* pos     = (int*)alloc((size_t)N_NODES * 4);
    int* elist   = (int*)alloc((size_t)N_EDGES * 4);
    unsigned int* h2b = h1b;  // h1b dead after agg1; 15.4MB >= 5.1MB needed

    hipMemsetAsync(deg, 0, (size_t)N_NODES * 4, stream);
    hist_kernel<<<(N_EDGES + 255) / 256, 256, 0, stream>>>(dst, deg);
    scan_kernel<<<1, 1024, 0, stream>>>(deg, offsets, pos);
    scatter_kernel<<<(N_EDGES + 255) / 256, 256, 0, stream>>>(src, dst, pos, elist);

    dim3 g1(N_NODES / 40, 3);
    gemm1_kernel<<<g1, 256, 0, stream>>>(feats, W1, al1, ar1, (uint2*)h1b, el1, er1);
    agg1_kernel<<<N_NODES, 192, 0, stream>>>(h1b, el1, er1, offsets, elist, b1, (float2*)x2);
    gemm2_kernel<<<N_NODES / 40, 256, 0, stream>>>(x2, W2, al2, ar2, (uint2*)h2b, el2, er2);
    agg2_kernel<<<N_NODES, 64, 0, stream>>>(h2b, el2, er2, offsets, elist, b2, (float2*)out);
}